// Round 10
// baseline (29.006 us; speedup 1.0000x reference)
//
#include <hip/hip_runtime.h>

#define NPIX  65536
#define NG    512
#define NB    4
#define MAXD  362.03867196751236f
#define WRAD  24                  // Chebyshev window radius for term-2 fast path
#define WDIM  49                  // 2*WRAD+1
#define WCNT  2401                // WDIM*WDIM
#define SAFE_Q (23.0f - MAXD)     // window min <= this => provably global
#define NBLK_T1 256               // term-1: (4 img) x (2 g-halves) x (32 row-groups)
#define NBLK_T2 (NB*NG)           // 2048
#define NBLK_MAIN (NBLK_T1 + NBLK_T2)
#define NBLK_CMB 128              // combine: (4 img) x (32 row-groups)

// ws layout (floats):
#define MPART_OFF 0               // [0, 524288): 256 blocks x 2048 partial-min floats
#define T2_OFF    524288          // [.., +2048): per-(b,g) min of p*(d-MAXD)
#define PD_OFF    526336          // [.., +128): combine-block partial sum p*d
#define PP_OFF    526464          // [.., +128): combine-block partial sum p
#define CNT_OFF   526592          // completion counter (memset 0 each call)

__device__ __forceinline__ float wave_sum(float v){
  #pragma unroll
  for (int o = 32; o > 0; o >>= 1) v += __shfl_down(v, o, 64);
  return v;
}
__device__ __forceinline__ float wave_min(float v){
  #pragma unroll
  for (int o = 32; o > 0; o >>= 1) v = fminf(v, __shfl_down(v, o, 64));
  return v;
}

// ---------- main: term-1 partial-min (blocks 0..255) + term-2 windows (256..2303) ----------
__global__ __launch_bounds__(256) void k_main(const float* __restrict__ prob,
                                              const int* __restrict__ gt,
                                              float* __restrict__ ws){
  const int tid = threadIdx.x;

  if (blockIdx.x < NBLK_T1){
    // ----- term 1 partial: block = (b, g-half, 8-row group); thread = column -----
    __shared__ float2 gsab[256];                    // (-2gh,-2gw) for my g-half (2KB)
    const int j    = blockIdx.x;
    const int b    = j >> 6;
    const int half = (j >> 5) & 1;
    const int rg   = j & 31;
    const int hp   = rg << 3;                       // rows hp..hp+7
    const float wf = (float)tid;

    {
      const int2 q = ((const int2*)gt)[b*NG + half*256 + tid];
      gsab[tid] = make_float2(-2.0f*(float)q.x, -2.0f*(float)q.y);
    }
    __syncthreads();

    float hf[8], m[8];
    #pragma unroll
    for (int r = 0; r < 8; ++r){ hf[r] = (float)(hp + r); m[r] = 3e38f; }

    // 2 g per iteration: fminf(fminf(m,t0),t1) -> v_min3_f32; 2.0 VALU per (px,g)
    #pragma unroll 4
    for (int k = 0; k < 128; ++k){
      const float2 q0 = gsab[2*k + 0];              // wave-uniform b64 broadcast
      const float2 q1 = gsab[2*k + 1];
      float sc0 = q0.x*q0.x; sc0 = fmaf(q0.y, q0.y, sc0) * 0.25f;  // gh^2+gw^2 exact
      float sc1 = q1.x*q1.x; sc1 = fmaf(q1.y, q1.y, sc1) * 0.25f;
      const float u0 = fmaf(q0.y, wf, sc0);         // sc - 2gw*w, exact int
      const float u1 = fmaf(q1.y, wf, sc1);
      #pragma unroll
      for (int r = 0; r < 8; ++r){
        const float t0 = fmaf(q0.x, hf[r], u0);     // d2 - (h^2+w^2), exact int
        const float t1 = fmaf(q1.x, hf[r], u1);
        m[r] = fminf(fminf(m[r], t0), t1);
      }
    }

    float* mp = ws + MPART_OFF + j*2048;
    #pragma unroll
    for (int r = 0; r < 8; ++r) mp[r*256 + tid] = m[r];   // coalesced
  } else {
    // ----- term 2: one (b,g) per block; window + exact in-block fallback -----
    __shared__ float red[8];
    const int idx = blockIdx.x - NBLK_T1;           // b*NG + g
    const int b   = idx >> 9;
    const int gh  = gt[idx*2 + 0];
    const int gw  = gt[idx*2 + 1];

    float qm = 3e38f;
    for (int i = tid; i < WCNT; i += 256){
      const int r  = i / WDIM;
      const int c  = i - r*WDIM;
      const int hh = gh - WRAD + r;
      const int ww = gw - WRAD + c;
      if ((unsigned)hh < 256u && (unsigned)ww < 256u){
        const float p  = prob[b*NPIX + hh*256 + ww];
        const int  dh  = r - WRAD, dw = c - WRAD;
        const float d  = __builtin_amdgcn_sqrtf((float)(dh*dh + dw*dw));
        qm = fminf(qm, fmaf(p, d, p * (-MAXD)));
      }
    }
    qm = wave_min(qm);
    const int wid = tid >> 6, lane = tid & 63;
    if (lane == 0) red[wid] = qm;
    __syncthreads();
    float qf = fminf(fminf(red[0], red[1]), fminf(red[2], red[3]));

    if (qf > SAFE_Q){
      // exact fallback: full-image rescan (block-uniform; practically never taken,
      // keeps the kernel exact for arbitrary inputs)
      const float ghf = (float)gh, gwf = (float)gw;
      const float aa  = -2.0f*ghf;
      const float wf  = (float)tid;
      const float bc  = fmaf(-2.0f*gwf, wf, fmaf(ghf, ghf, gwf*gwf));
      const float wsq = wf*wf;
      float q2 = 3e38f;
      const float* pr = prob + b*NPIX + tid;
      #pragma unroll 4
      for (int i = 0; i < 256; ++i){
        const float p   = pr[i*256];
        const float hfi = (float)i;
        const float d2v = fmaf(aa, hfi, fmaf(hfi, hfi, wsq) + bc);
        const float d   = __builtin_amdgcn_sqrtf(d2v);
        q2 = fminf(q2, fmaf(p, d, p * (-MAXD)));
      }
      q2 = wave_min(q2);
      __syncthreads();
      if (lane == 0) red[wid] = q2;
      __syncthreads();
      qf = fminf(fminf(red[0], red[1]), fminf(red[2], red[3]));
    }
    if (tid == 0) ws[T2_OFF + idx] = qf;
  }
}

// ---------- combine: min halves + weight + reduce; last block finishes ----------
__global__ __launch_bounds__(256) void k_combine(const float* __restrict__ prob,
                                                 float* __restrict__ ws,
                                                 float* __restrict__ out){
  const int tid = threadIdx.x;
  const int blk = blockIdx.x;                       // b*32 + rg
  const int b   = blk >> 5;
  const int rg  = blk & 31;
  const int hp  = rg << 3;
  __shared__ float red[8];
  __shared__ float t1sh[NB];
  __shared__ int   lastFlag;

  const float* mA = ws + MPART_OFF + (b*64 + rg)*2048;        // half 0
  const float* mB = ws + MPART_OFF + (b*64 + 32 + rg)*2048;   // half 1
  const int w2 = tid*tid;

  float spd = 0.0f, sp = 0.0f;
  #pragma unroll
  for (int r = 0; r < 8; ++r){
    const int h = hp + r;
    const float v = fminf(mA[r*256 + tid], mB[r*256 + tid]);
    const float d = __builtin_amdgcn_sqrtf(v + (float)(h*h + w2));
    const float p = prob[b*NPIX + h*256 + tid];
    spd = fmaf(p, d, spd);
    sp += p;
  }
  spd = wave_sum(spd);
  sp  = wave_sum(sp);
  const int wid = tid >> 6, lane = tid & 63;
  if (lane == 0){ red[wid] = spd; red[4+wid] = sp; }
  __syncthreads();
  if (tid == 0){
    ws[PD_OFF + blk] = (red[0]+red[1]) + (red[2]+red[3]);
    ws[PP_OFF + blk] = (red[4]+red[5]) + (red[6]+red[7]);
    __threadfence();                                 // release partials
    const unsigned t = atomicAdd((unsigned*)(ws + CNT_OFF), 1u);
    lastFlag = (t == NBLK_CMB - 1u);
  }
  __syncthreads();

  if (lastFlag){
    __threadfence();                                 // acquire all partials
    // term-2: sum 2048 per-(b,g) mins (written by previous kernel)
    float s = 0.0f;
    #pragma unroll
    for (int k = 0; k < 8; ++k) s += ws[T2_OFF + tid + 256*k];
    s = wave_sum(s);
    if (lane == 0) red[wid] = s;
    __syncthreads();

    if (tid < NB){
      float pd = 0.0f, pp = 0.0f;
      for (int k = 0; k < 32; ++k){
        pd += ws[PD_OFF + tid*32 + k];
        pp += ws[PP_OFF + tid*32 + k];
      }
      t1sh[tid] = pd / (pp + 1e-6f);
    }
    __syncthreads();

    if (tid == 0){
      const float s2    = (red[0]+red[1]) + (red[2]+red[3]);
      const float term2 = MAXD + s2 * (1.0f/2048.0f);
      const float term1 = ((t1sh[0]+t1sh[1]) + (t1sh[2]+t1sh[3])) * 0.25f;
      out[0] = term1 + term2;
    }
  }
}

extern "C" void kernel_launch(void* const* d_in, const int* in_sizes, int n_in,
                              void* d_out, int out_size, void* d_ws, size_t ws_size,
                              hipStream_t stream) {
  const float* prob = (const float*)d_in[0];
  const int*   gt   = (const int*)d_in[1];
  float* out = (float*)d_out;
  float* ws  = (float*)d_ws;

  hipMemsetAsync(ws + CNT_OFF, 0, 4, stream);        // reset completion counter
  hipLaunchKernelGGL(k_main,    dim3(NBLK_MAIN), dim3(256), 0, stream, prob, gt, ws);
  hipLaunchKernelGGL(k_combine, dim3(NBLK_CMB),  dim3(256), 0, stream, prob, ws, out);
}

// Round 13
// 28.486 us; speedup vs baseline: 1.0182x; 1.0182x over previous
//
#include <hip/hip_runtime.h>

#define NPIX  65536
#define NG    512
#define NB    4
#define MAXD  362.03867196751236f
#define WRAD  24                  // Chebyshev window radius for term-2 fast path
#define WDIM  49                  // 2*WRAD+1
#define WCNT  2401                // WDIM*WDIM
#define SAFE_Q (23.0f - MAXD)     // window min <= this => provably global
#define NBLK_T1 128               // term-1: 8 rows per block (4 img x 32 row-groups)
#define NBLK_T2 (NB*NG)           // 2048
#define NBLK_MAIN (NBLK_T1 + NBLK_T2)

// ws layout (floats):
//   [0,   128) : term-1 per-block partial sum of p*min_d   (img = blk>>5)
//   [512, 640) : term-1 per-block partial sum of p
//   [1024,3072): per-(b,g) min of p*(d - MAXD)

__device__ __forceinline__ float wave_sum(float v){
  #pragma unroll
  for (int o = 32; o > 0; o >>= 1) v += __shfl_down(v, o, 64);
  return v;
}
__device__ __forceinline__ float wave_min(float v){
  #pragma unroll
  for (int o = 32; o > 0; o >>= 1) v = fminf(v, __shfl_down(v, o, 64));
  return v;
}

// ---------- main: term-1 (blocks 0..127) + term-2 windows (blocks 128..2175) ----------
__global__ __launch_bounds__(256) void k_main(const float* __restrict__ prob,
                                              const int* __restrict__ gt,
                                              float* __restrict__ wsout){
  const int tid = threadIdx.x;

  if (blockIdx.x < NBLK_T1){
    // ----- term 1: block = (b, 8-row group); thread = column -----
    // transport: (-2gh,-2gw) in LDS (4KB), ds_read_b64 wave-uniform broadcast;
    // sc reconstructed in-register; 2 g per iter -> v_min3 (2.0 VALU per px*g).
    __shared__ float2 gsab[NG];
    __shared__ float red[8];
    const int b  = blockIdx.x >> 5;                 // 32 blocks per image
    const int hp = (blockIdx.x & 31) << 3;          // rows hp .. hp+7
    const float wf = (float)tid;

    const int2* gtp = ((const int2*)gt) + b*NG;
    #pragma unroll
    for (int s = 0; s < 2; ++s){
      const int g = tid + 256*s;
      const int2 q = gtp[g];
      gsab[g] = make_float2(-2.0f*(float)q.x, -2.0f*(float)q.y);
    }
    __syncthreads();

    float hf[8], m[8];
    #pragma unroll
    for (int r = 0; r < 8; ++r){ hf[r] = (float)(hp + r); m[r] = 3e38f; }

    #pragma unroll 4
    for (int k = 0; k < 256; ++k){
      const float2 q0 = gsab[2*k + 0];              // wave-uniform b64 broadcast
      const float2 q1 = gsab[2*k + 1];
      float sc0 = q0.x*q0.x; sc0 = fmaf(q0.y, q0.y, sc0) * 0.25f;  // gh^2+gw^2 exact
      float sc1 = q1.x*q1.x; sc1 = fmaf(q1.y, q1.y, sc1) * 0.25f;
      const float u0 = fmaf(q0.y, wf, sc0);         // sc - 2gw*w, exact int
      const float u1 = fmaf(q1.y, wf, sc1);
      #pragma unroll
      for (int r = 0; r < 8; ++r){
        const float t0 = fmaf(q0.x, hf[r], u0);     // d2 - (h^2+w^2), exact int
        const float t1 = fmaf(q1.x, hf[r], u1);
        m[r] = fminf(fminf(m[r], t0), t1);          // v_min3
      }
    }

    float spd = 0.0f, sp = 0.0f;
    const float w2 = (float)(tid*tid);
    #pragma unroll
    for (int r = 0; r < 8; ++r){
      const float d = __builtin_amdgcn_sqrtf(m[r] + fmaf(hf[r], hf[r], w2));
      const float p = prob[b*NPIX + (hp + r)*256 + tid];   // coalesced
      spd = fmaf(p, d, spd);
      sp += p;
    }

    spd = wave_sum(spd);
    sp  = wave_sum(sp);
    const int wid = tid >> 6, lane = tid & 63;
    if (lane == 0){ red[wid] = spd; red[4+wid] = sp; }
    __syncthreads();
    if (tid == 0){
      wsout[blockIdx.x]       = (red[0]+red[1]) + (red[2]+red[3]);
      wsout[512 + blockIdx.x] = (red[4]+red[5]) + (red[6]+red[7]);
    }
  } else {
    // ----- term 2: one (b,g) per block; window + exact in-block fallback -----
    __shared__ float red[8];
    const int idx = blockIdx.x - NBLK_T1;           // b*NG + g
    const int b   = idx >> 9;
    const int gh  = gt[idx*2 + 0];
    const int gw  = gt[idx*2 + 1];

    float qm = 3e38f;
    for (int i = tid; i < WCNT; i += 256){
      const int r  = i / WDIM;
      const int c  = i - r*WDIM;
      const int hh = gh - WRAD + r;
      const int ww = gw - WRAD + c;
      if ((unsigned)hh < 256u && (unsigned)ww < 256u){
        const float p  = prob[b*NPIX + hh*256 + ww];
        const int  dh  = r - WRAD, dw = c - WRAD;
        const float d  = __builtin_amdgcn_sqrtf((float)(dh*dh + dw*dw));
        qm = fminf(qm, fmaf(p, d, p * (-MAXD)));
      }
    }
    qm = wave_min(qm);
    const int wid = tid >> 6, lane = tid & 63;
    if (lane == 0) red[wid] = qm;
    __syncthreads();
    float qf = fminf(fminf(red[0], red[1]), fminf(red[2], red[3]));

    if (qf > SAFE_Q){
      // exact fallback: full-image rescan (block-uniform; practically never taken,
      // keeps the kernel exact for arbitrary inputs)
      const float ghf = (float)gh, gwf = (float)gw;
      const float aa  = -2.0f*ghf;
      const float wf  = (float)tid;
      const float bc  = fmaf(-2.0f*gwf, wf, fmaf(ghf, ghf, gwf*gwf));
      const float wsq = wf*wf;
      float q2 = 3e38f;
      const float* pr = prob + b*NPIX + tid;
      #pragma unroll 4
      for (int i = 0; i < 256; ++i){
        const float p   = pr[i*256];
        const float hfi = (float)i;
        const float d2v = fmaf(aa, hfi, fmaf(hfi, hfi, wsq) + bc);
        const float d   = __builtin_amdgcn_sqrtf(d2v);
        q2 = fminf(q2, fmaf(p, d, p * (-MAXD)));
      }
      q2 = wave_min(q2);
      __syncthreads();
      if (lane == 0) red[wid] = q2;
      __syncthreads();
      qf = fminf(fminf(red[0], red[1]), fminf(red[2], red[3]));
    }
    if (tid == 0) wsout[1024 + idx] = qf;
  }
}

// ---------- finish: fully parallel deterministic reduction ----------
__global__ __launch_bounds__(256) void k_finish(const float* __restrict__ ws,
                                                float* __restrict__ out){
  const int tid  = threadIdx.x;
  const int w    = tid >> 6;      // wave id == image id for term-1 part
  const int lane = tid & 63;
  __shared__ float redT2[4];
  __shared__ float t1sh[NB];

  // ---- term-2 sum: 2048 values, 8 per thread, coalesced, 1 latency exposure ----
  float s = 0.0f;
  #pragma unroll
  for (int j = 0; j < 8; ++j) s += ws[1024 + tid*8 + j];
  s = wave_sum(s);
  if (lane == 0) redT2[w] = s;

  // ---- term-1: wave w = image w; lanes 0-31 carry p*d partials, 32-63 carry p ----
  float v = (lane < 32) ? ws[w*32 + lane] : ws[512 + w*32 + (lane - 32)];
  #pragma unroll
  for (int o = 16; o > 0; o >>= 1) v += __shfl_down(v, o, 32);
  const float ppv = __shfl(v, 32, 64);              // pp total (from lane 32)
  if (lane == 0) t1sh[w] = v / (ppv + 1e-6f);
  __syncthreads();

  if (tid == 0){
    const float s2    = (redT2[0]+redT2[1]) + (redT2[2]+redT2[3]);
    const float term2 = MAXD + s2 * (1.0f/2048.0f);
    const float term1 = ((t1sh[0]+t1sh[1]) + (t1sh[2]+t1sh[3])) * 0.25f;
    out[0] = term1 + term2;
  }
}

extern "C" void kernel_launch(void* const* d_in, const int* in_sizes, int n_in,
                              void* d_out, int out_size, void* d_ws, size_t ws_size,
                              hipStream_t stream) {
  const float* prob = (const float*)d_in[0];
  const int*   gt   = (const int*)d_in[1];
  float* out = (float*)d_out;
  float* ws  = (float*)d_ws;

  hipLaunchKernelGGL(k_main,   dim3(NBLK_MAIN), dim3(256), 0, stream, prob, gt, ws);
  hipLaunchKernelGGL(k_finish, dim3(1),         dim3(256), 0, stream, ws, out);
}